// Round 3
// baseline (120.955 us; speedup 1.0000x reference)
//
#include <hip/hip_runtime.h>
#include <hip/hip_bf16.h>

typedef __attribute__((ext_vector_type(8))) short bf16x8;
typedef __attribute__((ext_vector_type(4))) float f32x4;
typedef __attribute__((ext_vector_type(4))) int int4v;

// Problem constants
#define NB 4
#define NN 4096
#define NC 256
#define NSPLIT 4
#define KEYS_PER_SPLIT 1024
#define KT_ITERS 16      // KEYS_PER_SPLIT / 64

__device__ __forceinline__ unsigned short f2bf(float f) {
    unsigned u = __builtin_bit_cast(unsigned, f);
    u += 0x7fffu + ((u >> 16) & 1u);   // round-to-nearest-even
    return (unsigned short)(u >> 16);
}
__device__ __forceinline__ float bf2f(unsigned short u) {
    unsigned v = ((unsigned)u) << 16;
    return __builtin_bit_cast(float, v);
}
__device__ __forceinline__ void load_lds16(const void* g, void* l) {
    __builtin_amdgcn_global_load_lds(
        (const __attribute__((address_space(1))) void*)g,
        (__attribute__((address_space(3))) void*)l, 16, 0, 0);
}

// ---------------- kernel 0: weight transpose + bf16 cast ----------------
__global__ __launch_bounds__(256) void wt_kernel(
    const float* __restrict__ wq, const float* __restrict__ wk,
    const float* __restrict__ wv, unsigned short* __restrict__ wt)
{
    const int c = blockIdx.x;     // 0..319
    const int k = threadIdx.x;    // 0..255
    float v;
    if (c < 32)      v = wq[k * 32 + c];
    else if (c < 64) v = wk[k * 32 + (c - 32)];
    else             v = wv[k * 256 + (c - 64)];
    wt[c * 256 + k] = f2bf(v);
}

// ---------------- kernel 1: QKV projection (MFMA, no LDS) ----------------
__global__ __launch_bounds__(256) void proj_kernel(
    const float* __restrict__ x,              // [16384][256]
    const unsigned short* __restrict__ wt,    // [320][256] = W^T bf16
    const float* __restrict__ bq, const float* __restrict__ bk,
    const float* __restrict__ bv,
    unsigned short* __restrict__ q_ws,
    unsigned short* __restrict__ k_ws,
    unsigned short* __restrict__ vt_ws)
{
    const int lane = threadIdx.x & 63;
    const int w    = threadIdx.x >> 6;
    const int l15  = lane & 15, hh = lane >> 4;
    const int m0   = blockIdx.x * 16;      // 16 rows per block
    const int ct0  = w * 5;                // this wave's 5 col-groups

    f32x4 acc[5];
    #pragma unroll
    for (int i = 0; i < 5; ++i) acc[i] = f32x4{0.f, 0.f, 0.f, 0.f};

    const float* xrow = x + (size_t)(m0 + l15) * 256 + hh * 8;
    #pragma unroll
    for (int ks = 0; ks < 8; ++ks) {
        float4 xa = ((const float4*)(xrow + ks * 32))[0];
        float4 xb = ((const float4*)(xrow + ks * 32))[1];
        bf16x8 afrag;
        afrag[0] = (short)f2bf(xa.x); afrag[1] = (short)f2bf(xa.y);
        afrag[2] = (short)f2bf(xa.z); afrag[3] = (short)f2bf(xa.w);
        afrag[4] = (short)f2bf(xb.x); afrag[5] = (short)f2bf(xb.y);
        afrag[6] = (short)f2bf(xb.z); afrag[7] = (short)f2bf(xb.w);
        #pragma unroll
        for (int c = 0; c < 5; ++c) {
            bf16x8 bfrag = *(const bf16x8*)(wt + (size_t)((ct0 + c) * 16 + l15) * 256 + ks * 32 + hh * 8);
            acc[c] = __builtin_amdgcn_mfma_f32_16x16x32_bf16(afrag, bfrag, acc[c], 0, 0, 0);
        }
    }

    const int b    = m0 >> 12;
    const int nloc = m0 & 4095;
    #pragma unroll
    for (int c = 0; c < 5; ++c) {
        const int ct = ct0 + c;
        const int c0 = ct * 16;
        float bias;
        if (c0 < 32)      bias = bq[c0 + l15];
        else if (c0 < 64) bias = bk[c0 - 32 + l15];
        else              bias = bv[c0 - 64 + l15];
        if (c0 < 64) {
            unsigned short* dst = (c0 < 32) ? q_ws : k_ws;
            const int cc = (c0 < 32) ? c0 : (c0 - 32);
            #pragma unroll
            for (int i = 0; i < 4; ++i)
                dst[(size_t)(m0 + hh * 4 + i) * 32 + cc + l15] = f2bf(acc[c][i] + bias);
        } else {
            const int cc = c0 - 64 + l15;
            #pragma unroll
            for (int i = 0; i < 4; i += 2) {
                unsigned lo = f2bf(acc[c][i]     + bias);
                unsigned hi = f2bf(acc[c][i + 1] + bias);
                *(unsigned*)(vt_ws + ((size_t)b * 256 + cc) * 4096 + nloc + hh * 4 + i)
                    = lo | (hi << 16);
            }
        }
    }
}

// ---------------- kernel 2: flash attention ----------------
// grid = 512 blocks of 512 threads (8 waves). Block: 128 q-rows, 1024 keys.
// XCD-swizzled so each XCD owns 2 (split,batch) combos (V working set = L2).
// QK: wave (wr = wid>>2, kc = wid&3): rows wr*64 + qt*16, keys kc*16.
// PV: wave (wr, wcol = wid&3): rows wr*64..+64, cols wcol*64..+64.
__global__ __launch_bounds__(512, 4) void attn_kernel(
    const unsigned short* __restrict__ q_ws,
    const unsigned short* __restrict__ k_ws,
    const unsigned short* __restrict__ vt_ws,
    unsigned short* __restrict__ opart,   // [4][4][4096][256] bf16 (unnormalized)
    float* __restrict__ lpart)            // [4][4][4096] f32
{
    __shared__ unsigned short vt_lds[256 * 64];  // [c][key], 128B rows, XOR-swizzled
    __shared__ unsigned short p_lds[128 * 64];   // [qrow][key], swizzled

    const int lane = threadIdx.x & 63;
    const int wid  = threadIdx.x >> 6;
    const int l15  = lane & 15, hh = lane >> 4;

    // XCD-aware decomposition: xcd = blockIdx & 7 owns combos {2*xcd, 2*xcd+1}
    const int xcd   = blockIdx.x & 7;
    const int j     = blockIdx.x >> 3;          // 0..63
    const int combo = xcd * 2 + (j >> 5);       // 0..15
    const int qtile = j & 31;
    const int split = combo >> 2;
    const int b     = combo & 3;
    const int q0    = qtile * 128;
    const int key0  = split * KEYS_PER_SPLIT;

    const int wr   = wid >> 2;          // row half (64 rows)
    const int kc   = wid & 3;           // QK key group / PV col group

    // persistent Q A-frags: rows q0 + wr*64 + qt*16 + l15
    bf16x8 aq[4];
    #pragma unroll
    for (int qt = 0; qt < 4; ++qt)
        aq[qt] = *(const bf16x8*)(q_ws + (size_t)(b * 4096 + q0 + wr * 64 + qt * 16 + l15) * 32 + hh * 8);

    f32x4 acc[4][4];
    float lsum[4][4];
    #pragma unroll
    for (int qt = 0; qt < 4; ++qt) {
        #pragma unroll
        for (int ct = 0; ct < 4; ++ct) acc[qt][ct] = f32x4{0.f, 0.f, 0.f, 0.f};
        #pragma unroll
        for (int i = 0; i < 4; ++i) lsum[qt][i] = 0.f;
    }

    const unsigned short* vt_base = vt_ws + (size_t)b * 256 * 4096;
    const unsigned short* k_base  = k_ws + (size_t)b * 4096 * 32;

    for (int kt = 0; kt < KT_ITERS; ++kt) {
        const int kb = key0 + kt * 64;
        __syncthreads();   // prev iter's LDS reads complete

        // ---- async stage V^T tile (32KB): linear LDS dest, pre-swizzled src ----
        #pragma unroll
        for (int e = 0; e < 4; ++e) {
            int idx  = e * 512 + threadIdx.x;    // 16B chunk id, 0..2047
            int c    = idx >> 3;
            int slot = idx & 7;
            const unsigned short* src = vt_base + (size_t)c * 4096 + kb + ((slot ^ (c & 7)) << 3);
            load_lds16(src, (char*)vt_lds + idx * 16);
        }

        // ---- QK: rows wr*64+qt*16, keys kc*16 ----
        bf16x8 bkf = *(const bf16x8*)(k_base + (size_t)(kb + kc * 16 + l15) * 32 + hh * 8);
        f32x4 e2[4];
        #pragma unroll
        for (int qt = 0; qt < 4; ++qt) {
            f32x4 z = {0.f, 0.f, 0.f, 0.f};
            e2[qt] = __builtin_amdgcn_mfma_f32_16x16x32_bf16(aq[qt], bkf, z, 0, 0, 0);
        }

        // ---- p = exp(e), write P swizzled, accumulate l ----
        #pragma unroll
        for (int qt = 0; qt < 4; ++qt) {
            #pragma unroll
            for (int i = 0; i < 4; ++i) {
                float p = __expf(e2[qt][i]);
                lsum[qt][i] += p;
                int r   = wr * 64 + qt * 16 + hh * 4 + i;
                int off = kc * 32 + l15 * 2;
                int sw  = (((off >> 4) ^ (r & 7)) << 4) | (off & 15);
                *(unsigned short*)((char*)p_lds + r * 128 + sw) = f2bf(p);
            }
        }
        __syncthreads();   // V staged (vmcnt drained) + P visible

        // ---- PV: rows wr*64..+64, cols kc*64..+64 ----
        __builtin_amdgcn_s_setprio(1);
        #pragma unroll
        for (int s = 0; s < 2; ++s) {
            bf16x8 ap[4];
            #pragma unroll
            for (int qt = 0; qt < 4; ++qt) {
                int r = wr * 64 + qt * 16 + l15;
                ap[qt] = *(const bf16x8*)((char*)p_lds + r * 128 + (((s * 4 + hh) ^ (r & 7)) << 4));
            }
            #pragma unroll
            for (int ct = 0; ct < 4; ++ct) {
                int c = kc * 64 + ct * 16 + l15;
                bf16x8 bvf = *(const bf16x8*)((char*)vt_lds + c * 128 + (((s * 4 + hh) ^ (c & 7)) << 4));
                #pragma unroll
                for (int qt = 0; qt < 4; ++qt)
                    acc[qt][ct] = __builtin_amdgcn_mfma_f32_16x16x32_bf16(ap[qt], bvf, acc[qt][ct], 0, 0, 0);
            }
        }
        __builtin_amdgcn_s_setprio(0);
    }

    // ---- epilogue: l reduction via p_lds scratch, write partials ----
    __syncthreads();                       // done with p_lds as bf16 P
    float* l_s = (float*)p_lds;            // [4 kc][128 rows] f32
    #pragma unroll
    for (int qt = 0; qt < 4; ++qt) {
        #pragma unroll
        for (int i = 0; i < 4; ++i) {
            float s = lsum[qt][i];
            s += __shfl_xor(s, 1); s += __shfl_xor(s, 2);
            s += __shfl_xor(s, 4); s += __shfl_xor(s, 8);
            if (l15 == 0) l_s[kc * 128 + wr * 64 + qt * 16 + hh * 4 + i] = s;
        }
    }
    __syncthreads();

    const size_t rowbase = (size_t)(split * 4 + b) * 4096 + q0 + wr * 64;
    if (kc == 0 && l15 == 0) {
        #pragma unroll
        for (int qt = 0; qt < 4; ++qt) {
            #pragma unroll
            for (int i = 0; i < 4; ++i) {
                int row = wr * 64 + qt * 16 + hh * 4 + i;
                lpart[rowbase + qt * 16 + hh * 4 + i] =
                    l_s[row] + l_s[128 + row] + l_s[256 + row] + l_s[384 + row];
            }
        }
    }

    #pragma unroll
    for (int qt = 0; qt < 4; ++qt) {
        #pragma unroll
        for (int i = 0; i < 4; ++i) {
            int r = qt * 16 + hh * 4 + i;
            #pragma unroll
            for (int ct = 0; ct < 4; ++ct) {
                int c = kc * 64 + ct * 16 + l15;
                opart[(rowbase + r) * 256 + c] = f2bf(acc[qt][ct][i]);
            }
        }
    }
}

// ---------------- kernel 3: combine splits + residual ----------------
__global__ __launch_bounds__(256) void combine_kernel(
    const unsigned short* __restrict__ opart,
    const float* __restrict__ lpart,
    const float* __restrict__ x,
    const float* __restrict__ gamma_p,
    float* __restrict__ out)
{
    const int t  = blockIdx.x * 256 + threadIdx.x;   // 0..524287
    const int r  = t >> 5;                           // global row 0..16383
    const int c0 = (t & 31) * 8;
    const float gamma = gamma_p[0];

    float sumO[8];
    #pragma unroll
    for (int j = 0; j < 8; ++j) sumO[j] = 0.f;
    float suml = 0.f;
    #pragma unroll
    for (int s = 0; s < NSPLIT; ++s) {
        bf16x8 o = *(const bf16x8*)(opart + ((size_t)(s * 16384 + r)) * 256 + c0);
        #pragma unroll
        for (int j = 0; j < 8; ++j) sumO[j] += bf2f((unsigned short)o[j]);
        suml += lpart[s * 16384 + r];
    }
    const float inv = gamma / suml;
    const size_t base = (size_t)r * 256 + c0;
    float4 x0 = *(const float4*)(x + base);
    float4 x1 = *(const float4*)(x + base + 4);
    float4 o0, o1;
    o0.x = sumO[0] * inv + x0.x; o0.y = sumO[1] * inv + x0.y;
    o0.z = sumO[2] * inv + x0.z; o0.w = sumO[3] * inv + x0.w;
    o1.x = sumO[4] * inv + x1.x; o1.y = sumO[5] * inv + x1.y;
    o1.z = sumO[6] * inv + x1.z; o1.w = sumO[7] * inv + x1.w;
    *(float4*)(out + base)     = o0;
    *(float4*)(out + base + 4) = o1;
}

extern "C" void kernel_launch(void* const* d_in, const int* in_sizes, int n_in,
                              void* d_out, int out_size, void* d_ws, size_t ws_size,
                              hipStream_t stream) {
    const float* x     = (const float*)d_in[0];
    const float* wq    = (const float*)d_in[1];
    const float* bq    = (const float*)d_in[2];
    const float* wk    = (const float*)d_in[3];
    const float* bk    = (const float*)d_in[4];
    const float* wv    = (const float*)d_in[5];
    const float* bv    = (const float*)d_in[6];
    const float* gamma = (const float*)d_in[7];
    float* out = (float*)d_out;

    char* ws = (char*)d_ws;
    unsigned short* wt    = (unsigned short*)(ws);                  // 160KB
    unsigned short* q_ws  = (unsigned short*)(ws + 163840);         // 1MB
    unsigned short* k_ws  = (unsigned short*)(ws + 1212416);        // 1MB
    unsigned short* vt_ws = (unsigned short*)(ws + 2260992);        // 8MB
    unsigned short* opart = (unsigned short*)(ws + 10649600);       // 32MB
    float*          lpart = (float*)(ws + 44204032);                // 256KB

    wt_kernel     <<<320,  256, 0, stream>>>(wq, wk, wv, wt);
    proj_kernel   <<<1024, 256, 0, stream>>>(x, wt, bq, bk, bv, q_ws, k_ws, vt_ws);
    attn_kernel   <<<512,  512, 0, stream>>>(q_ws, k_ws, vt_ws, opart, lpart);
    combine_kernel<<<2048, 256, 0, stream>>>(opart, lpart, x, gamma, out);
}